// Round 9
// baseline (186.325 us; speedup 1.0000x reference)
//
#include <hip/hip_runtime.h>
#include <hip/hip_bf16.h>
#include <stdint.h>

#define B_SZ   2048
#define DDATA  768
#define NSAE   128
#define NJK    4096   // NSAE*32
#define KA2    4352   // NJK + 128 (acts0) + 128 (gate)
#define SPLITK 2
#define KC2    2176   // KA2 / SPLITK (34 x BK=64)
#define GZCH   8      // gate d-chunks
#define GZW    96     // DDATA / GZCH

typedef unsigned short u16;
typedef short bf16x8 __attribute__((ext_vector_type(8)));
typedef float f32x4  __attribute__((ext_vector_type(4)));

static __device__ __forceinline__ u16 f2bf(float f) {
  __hip_bfloat16 h = __float2bfloat16(f);
  return *reinterpret_cast<u16*>(&h);
}

static __device__ __forceinline__ void gload16(const u16* g, u16* l) {
  __builtin_amdgcn_global_load_lds(
      (const __attribute__((address_space(1))) unsigned int*)g,
      (__attribute__((address_space(3))) unsigned int*)l,
      16, 0, 0);
}

// ======== k_front: all input-independent work in ONE kernel ========
// blocks    0..127 : expert j: transpose We1[j]->W1T + cv = be1 - bd1[j]@We1[j]
// blocks  128..943 : B2T build ([W_dec1 ; W_dec0 ; b_dec1]^T), 68 rb x 12 dbk
// blocks  944..951 : wn[j] = ||We0[:,j]||  (flag threshold)
// blocks 952..1463 : gate partials pp[z][b][j] (+ fused x->bf16 cast, xnp=||x||^2 partial)
__global__ __launch_bounds__(256) void k_front(const float* __restrict__ x,
                                               const float* __restrict__ We0,
                                               const float* __restrict__ bd0,
                                               const float* __restrict__ We1,
                                               const float* __restrict__ bd1,
                                               const float* __restrict__ be1,
                                               const float* __restrict__ Wd1,
                                               const float* __restrict__ Wd0,
                                               u16* __restrict__ W1T,
                                               float* __restrict__ cv,
                                               u16* __restrict__ B2T,
                                               u16* __restrict__ xb,
                                               float* __restrict__ pp,
                                               float* __restrict__ xnp,
                                               float* __restrict__ wn) {
  __shared__ float smem[64 * 65];                 // 16.6 KB shared by all branches
  const int bid = blockIdx.x, t = threadIdx.x;
  if (bid < 128) {
    const int j = bid;
    float* ts  = smem;                            // 64*33
    float* bds = smem + 64 * 33;                  // 64
    float* red = smem + 64 * 33 + 64;             // 8*32
    const int k = t & 31, g = t >> 5;
    float cacc = 0.f;
    for (int db = 0; db < 12; ++db) {
      const float* src = We1 + (size_t)j * 24576 + db * 2048;  // 64 d x 32 k
#pragma unroll
      for (int i = 0; i < 8; ++i) {
        int e = t + i * 256;
        ts[(e >> 5) * 33 + (e & 31)] = src[e];
      }
      if (t < 64) bds[t] = bd1[(size_t)j * DDATA + db * 64 + t];
      __syncthreads();
#pragma unroll
      for (int i = 0; i < 8; ++i) {
        int e = t + i * 256;
        int kk = e >> 6, d = e & 63;
        W1T[(size_t)(j * 32 + kk) * DDATA + db * 64 + d] = f2bf(ts[d * 33 + kk]);
      }
#pragma unroll
      for (int q = 0; q < 8; ++q) {
        int d = g + 8 * q;
        cacc += ts[d * 33 + k] * bds[d];
      }
      __syncthreads();
    }
    red[g * 32 + k] = cacc;
    __syncthreads();
    if (g == 0) {
      float s = 0.f;
#pragma unroll
      for (int q = 0; q < 8; ++q) s += red[q * 32 + k];
      cv[j * 32 + k] = be1[j * 32 + k] - s;
    }
  } else if (bid < 944) {
    const int e2 = bid - 128;
    const int rb = e2 / 12, dbk = e2 % 12;
    const float* src; int r0, base;
    if (rb < 64)      { src = Wd1; r0 = rb * 64;        base = 0;    }
    else if (rb < 66) { src = Wd0; r0 = (rb - 64) * 64; base = 4096; }
    else              { src = bd1; r0 = (rb - 66) * 64; base = 4224; }
    const int d0 = dbk * 64;
#pragma unroll
    for (int i = 0; i < 16; ++i) {
      int e = t + i * 256;
      int ri = e >> 6, di = e & 63;
      smem[ri * 65 + di] = src[(size_t)(r0 + ri) * DDATA + d0 + di];
    }
    __syncthreads();
#pragma unroll
    for (int i = 0; i < 16; ++i) {
      int e = t + i * 256;
      int di = e >> 6, ri = e & 63;
      B2T[(size_t)(d0 + di) * KA2 + base + r0 + ri] = f2bf(smem[ri * 65 + di]);
    }
  } else if (bid < 952) {
    const int wb = bid - 944;                     // 16 j per block
    const int jj = wb * 16 + (t >> 4), s = t & 15;
    float acc = 0.f;
    for (int d = s; d < DDATA; d += 16) {
      float w = We0[(size_t)d * 128 + jj];
      acc += w * w;
    }
#pragma unroll
    for (int sh = 8; sh; sh >>= 1) acc += __shfl_xor(acc, sh, 64);
    if (s == 0) wn[jj] = sqrtf(acc);
  } else {
    const int bid2 = bid - 952;
    const int b0 = (bid2 & 63) * 32, z = bid2 >> 6;
    const int dbase = z * GZW;
    float* xs = smem;                             // 32*96 = 12 KB
#pragma unroll
    for (int i = 0; i < 3; ++i) {
      int idx = t + i * 256;                      // 32 rows x 24 float4
      int r = idx / 24, c4 = idx % 24;
      size_t go = (size_t)(b0 + r) * DDATA + dbase + c4 * 4;
      float4 v = *(const float4*)&x[go];
      ushort4 o;
      o.x = f2bf(v.x); o.y = f2bf(v.y); o.z = f2bf(v.z); o.w = f2bf(v.w);
      *(ushort4*)&xb[go] = o;                     // fused xcast
      float4 b4 = *(const float4*)&bd0[dbase + c4 * 4];
      v.x -= b4.x; v.y -= b4.y; v.z -= b4.z; v.w -= b4.w;
      *(float4*)&xs[r * GZW + c4 * 4] = v;
    }
    __syncthreads();
    const int jp = t & 63, rg = t >> 6;           // wave-uniform rg
    const int j0 = jp * 2;
    float ap[8][2], xq[8];
#pragma unroll
    for (int r = 0; r < 8; ++r) { ap[r][0] = ap[r][1] = xq[r] = 0.f; }
    for (int d = 0; d < GZW; d += 4) {
      float4 xv[8];
#pragma unroll
      for (int r = 0; r < 8; ++r)
        xv[r] = *(const float4*)&xs[(rg * 8 + r) * GZW + d];
#pragma unroll
      for (int dd = 0; dd < 4; ++dd) {
        float2 w2 = *(const float2*)&We0[(size_t)(dbase + d + dd) * 128 + j0];
#pragma unroll
        for (int r = 0; r < 8; ++r) {
          float xr = ((const float*)&xv[r])[dd];
          ap[r][0] += xr * w2.x;
          ap[r][1] += xr * w2.y;
          xq[r]    += xr * xr;
        }
      }
    }
#pragma unroll
    for (int r = 0; r < 8; ++r) {
      size_t o = ((size_t)z * B_SZ + b0 + rg * 8 + r) * 128 + j0;
      *(float2*)&pp[o] = make_float2(ap[r][0], ap[r][1]);
    }
    if (jp == 0) {
#pragma unroll
      for (int r = 0; r < 8; ++r)
        xnp[(size_t)z * B_SZ + b0 + rg * 8 + r] = xq[r];
    }
  }
}

// ------ GEMM: C = A[M,K] * B^T[N,K], bf16 MFMA 16x16x32, BK=64, XOR-swizzled LDS ------
// EPI=1 (fused gate): after K-loop, compute this block's 128x4 gate slice from
//   pp/xnp/wn (+ rare wave-coop fp64 fix-up), write acts0/gate cols to A2, then
//   epilogue v = relu(v + c[gn]) * gate -> packed bf16x2 into A2[:,0..4095]
// EPI=2: part[bz][gm][gn] = v  (split-K fp32, reduced by k_reduce)
template<int BM, int BN, int EPI>
__global__ __launch_bounds__(256) void k_gemm(const u16* __restrict__ A,
                                              const u16* __restrict__ Bm,
                                              int K, int Kc,
                                              float* __restrict__ outF,
                                              u16* __restrict__ A2,
                                              const float* __restrict__ cvec,
                                              const float* __restrict__ pp,
                                              const float* __restrict__ xnp,
                                              const float* __restrict__ wnv,
                                              const float* __restrict__ be0,
                                              const float* __restrict__ x,
                                              const float* __restrict__ We0,
                                              const float* __restrict__ bd0) {
  constexpr int WM = BM / 32, WN = BN / 32;
  __shared__ __align__(16) u16 As[BM * 64];
  __shared__ __align__(16) u16 Bs[BN * 64];
  __shared__ u16 gate_s[BM * 4];
  __shared__ float cv_s[BN];
  const int tid = threadIdx.x;
  const int bx = blockIdx.x, by = blockIdx.y, bz = blockIdx.z;
  const int kbase = bz * Kc;
  const u16* Ab = A  + (size_t)(by * BM) * K;
  const u16* Bb = Bm + (size_t)(bx * BN) * K;
  const int wave = tid >> 6, lane = tid & 63;
  const int wr = wave >> 1, wc = wave & 1;
  const int m0 = wr * (BM / 2), n0 = wc * (BN / 2);
  const int lm = lane & 15, qd = lane >> 4;

  f32x4 acc[WM][WN];
  const f32x4 zero = {0.f, 0.f, 0.f, 0.f};
  for (int mi = 0; mi < WM; ++mi)
    for (int ni = 0; ni < WN; ++ni) acc[mi][ni] = zero;

  for (int k0 = kbase; k0 < kbase + Kc; k0 += 64) {
#pragma unroll
    for (int i = 0; i < BM / 32; ++i) {
      int id = tid + 256 * i;
      int row = id >> 3, u = id & 7;
      gload16(Ab + (size_t)row * K + k0 + ((u ^ (row & 7)) * 8), &As[id * 8]);
    }
#pragma unroll
    for (int i = 0; i < BN / 32; ++i) {
      int id = tid + 256 * i;
      int row = id >> 3, u = id & 7;
      gload16(Bb + (size_t)row * K + k0 + ((u ^ (row & 7)) * 8), &Bs[id * 8]);
    }
    __syncthreads();
#pragma unroll
    for (int s = 0; s < 2; ++s) {
      const int swz = ((s << 2) + qd) ^ (lm & 7);
      bf16x8 af[WM], bfv[WN];
#pragma unroll
      for (int mi = 0; mi < WM; ++mi)
        af[mi] = *(const bf16x8*)&As[(m0 + mi * 16 + lm) * 64 + swz * 8];
#pragma unroll
      for (int ni = 0; ni < WN; ++ni)
        bfv[ni] = *(const bf16x8*)&Bs[(n0 + ni * 16 + lm) * 64 + swz * 8];
#pragma unroll
      for (int mi = 0; mi < WM; ++mi)
#pragma unroll
        for (int ni = 0; ni < WN; ++ni)
          acc[mi][ni] = __builtin_amdgcn_mfma_f32_16x16x32_bf16(af[mi], bfv[ni],
                                                                acc[mi][ni], 0, 0, 0);
    }
    __syncthreads();
  }

  if (EPI == 1) {
    // ---- fused gate: 128 rows x 4 experts for this block, from pp/xnp/wn ----
#pragma unroll
    for (int e0 = 0; e0 < BM * 4; e0 += 256) {
      int e = e0 + tid;                           // 2 pairs per thread
      int r = e >> 2, q = e & 3;
      int gb = by * BM + r, gj = bx * 4 + q;
      float p = be0[gj], xn2 = 0.f;
#pragma unroll
      for (int z = 0; z < GZCH; ++z) {
        p   += pp[((size_t)z * B_SZ + gb) * 128 + gj];
        xn2 += xnp[(size_t)z * B_SZ + gb];
      }
      float tau = 1e-4f * sqrtf(xn2) * wnv[gj];
      // fp32 sign uncertain -> whole wave cooperates on exact fp64 recompute
      unsigned long long mask = __ballot(fabsf(p) <= tau);
      while (mask) {
        int src = (int)__builtin_ctzll(mask);
        mask &= mask - 1;
        int bb = __shfl(gb, src, 64), jj = __shfl(gj, src, 64);
        double dacc = 0.0;
#pragma unroll
        for (int tt = 0; tt < 12; ++tt) {
          int d = lane + tt * 64;
          dacc += (double)(x[(size_t)bb * DDATA + d] - bd0[d]) *
                  (double)We0[(size_t)d * 128 + jj];
        }
#pragma unroll
        for (int s = 32; s; s >>= 1) dacc += __shfl_xor(dacc, s, 64);
        double pd = dacc + (double)be0[jj];
        if (lane == src) p = (float)pd;
      }
      u16 gbit = (p > 0.f) ? (u16)0x3F80 : (u16)0;
      gate_s[e] = gbit;
      size_t row = (size_t)gb * KA2;
      A2[row + NJK + gj]       = f2bf(p > 0.f ? p : 0.f);   // acts0 col
      A2[row + NJK + 128 + gj] = gbit;                      // gate col
    }
    for (int e = tid; e < BN; e += 256) cv_s[e] = cvec[bx * BN + e];
    __syncthreads();
  }

  const int rb = qd * 4;
#pragma unroll
  for (int mi = 0; mi < WM; ++mi) {
#pragma unroll
    for (int ni = 0; ni < WN; ++ni) {
#pragma unroll
      for (int r = 0; r < 4; ++r) {
        int ml = m0 + mi * 16 + rb + r;
        int nl = n0 + ni * 16 + lm;
        int gm = by * BM + ml;
        int gn = bx * BN + nl;
        float v = acc[mi][ni][r];
        if (EPI == 1) {
          v += cv_s[nl];
          v = v > 0.f ? v : 0.f;
          u16 gbit = gate_s[ml * 4 + (nl >> 5)];
          v = gbit ? v : 0.f;
          float vn = __shfl_xor(v, 1, 64);        // pack even/odd columns
          if ((lm & 1) == 0) {
            unsigned pk = (unsigned)f2bf(v) | ((unsigned)f2bf(vn) << 16);
            *(unsigned*)&A2[(size_t)gm * KA2 + gn] = pk;
          }
        } else {
          outF[((size_t)bz * B_SZ + gm) * DDATA + gn] = v;
        }
      }
    }
  }
}

// ---------------- reduce split-K partials + bias ----------------
__global__ __launch_bounds__(256) void k_reduce(const float* __restrict__ part,
                                                const float* __restrict__ bias,
                                                float* __restrict__ out) {
  const int N4 = B_SZ * DDATA / 4;
  int i = blockIdx.x * 256 + threadIdx.x;
  const float4* p4 = (const float4*)part;
  float4 s = p4[i];
#pragma unroll
  for (int z = 1; z < SPLITK; ++z) {
    float4 t = p4[i + z * N4];
    s.x += t.x; s.y += t.y; s.z += t.z; s.w += t.w;
  }
  float4 b = ((const float4*)bias)[i % (DDATA / 4)];
  s.x += b.x; s.y += b.y; s.z += b.z; s.w += b.w;
  ((float4*)out)[i] = s;
}

extern "C" void kernel_launch(void* const* d_in, const int* in_sizes, int n_in,
                              void* d_out, int out_size, void* d_ws, size_t ws_size,
                              hipStream_t stream) {
  const float* x   = (const float*)d_in[0];
  const float* We0 = (const float*)d_in[1];
  const float* be0 = (const float*)d_in[2];
  const float* Wd0 = (const float*)d_in[3];
  const float* bd0 = (const float*)d_in[4];
  const float* We1 = (const float*)d_in[5];
  const float* be1 = (const float*)d_in[6];
  const float* Wd1 = (const float*)d_in[7];
  const float* bd1 = (const float*)d_in[8];
  float* out = (float*)d_out;

  uint8_t* ws = (uint8_t*)d_ws;
  size_t off = 0;
  auto carve = [&](size_t bytes) {
    uint8_t* p = ws + off;
    off += (bytes + 255) & ~(size_t)255;
    return p;
  };
  u16*    A2   = (u16*)carve((size_t)B_SZ * KA2 * 2);
  u16*    xb   = (u16*)carve((size_t)B_SZ * DDATA * 2);
  u16*    W1T  = (u16*)carve((size_t)NJK * DDATA * 2);
  u16*    B2T  = (u16*)carve((size_t)DDATA * KA2 * 2);
  float*  cv   = (float*)carve((size_t)NJK * 4);
  float*  part = (float*)carve((size_t)SPLITK * B_SZ * DDATA * 4);   // 12.6 MB
  float*  pp   = (float*)carve((size_t)GZCH * B_SZ * 128 * 4);       // 8.4 MB
  float*  xnp  = (float*)carve((size_t)GZCH * B_SZ * 4);             // 64 KB
  float*  wn   = (float*)carve(128 * 4);

  // all input-independent prep + gate partials, one kernel (pipes overlap)
  k_front <<<1464, 256, 0, stream>>>(x, We0, bd0, We1, bd1, be1, Wd1, Wd0,
                                     W1T, cv, B2T, xb, pp, xnp, wn);
  // GEMM1 + fused gate reduce/fix-up: acts1+acts0+gate -> A2  (M=2048,N=4096,K=768)
  k_gemm<128, 128, 1><<<dim3(32, 16, 1), 256, 0, stream>>>(
      xb, W1T, DDATA, DDATA, nullptr, A2, cv, pp, xnp, wn, be0, x, We0, bd0);
  // GEMM2 split-K: part[z] = A2 @ B2 over K-chunk z   (M=2048, N=768, K=4352)
  k_gemm<64, 128, 2><<<dim3(6, 32, SPLITK), 256, 0, stream>>>(
      A2, B2T, KA2, KC2, part, nullptr, nullptr,
      nullptr, nullptr, nullptr, nullptr, nullptr, nullptr, nullptr);
  k_reduce<<<1536, 256, 0, stream>>>(part, bd0, out);
}

// Round 10
// 165.915 us; speedup vs baseline: 1.1230x; 1.1230x over previous
//
#include <hip/hip_runtime.h>
#include <hip/hip_bf16.h>
#include <stdint.h>

#define B_SZ   2048
#define DDATA  768
#define NSAE   128
#define NJK    4096   // NSAE*32
#define KA2    4352   // NJK + 128 (acts0) + 128 (gate)
#define SPLITK 2
#define KC2    2176   // KA2 / SPLITK (34 x BK=64)
#define GZCH   8      // gate d-chunks
#define GZW    96     // DDATA / GZCH

typedef unsigned short u16;
typedef short bf16x8 __attribute__((ext_vector_type(8)));
typedef float f32x4  __attribute__((ext_vector_type(4)));

static __device__ __forceinline__ u16 f2bf(float f) {
  __hip_bfloat16 h = __float2bfloat16(f);
  return *reinterpret_cast<u16*>(&h);
}

static __device__ __forceinline__ void gload16(const u16* g, u16* l) {
  __builtin_amdgcn_global_load_lds(
      (const __attribute__((address_space(1))) unsigned int*)g,
      (__attribute__((address_space(3))) unsigned int*)l,
      16, 0, 0);
}

// ======== k_front: all input-independent work in ONE kernel ========
// blocks    0..127 : expert j: transpose We1[j]->W1T + cv = be1 - bd1[j]@We1[j]
// blocks  128..943 : B2T build ([W_dec1 ; W_dec0 ; b_dec1]^T), 68 rb x 12 dbk
// blocks  944..951 : wn[j] = ||We0[:,j]||  (flag threshold)
// blocks 952..1463 : gate partials pp[z][b][j] (+ fused x->bf16 cast, xnp=||x||^2 partial)
__global__ __launch_bounds__(256) void k_front(const float* __restrict__ x,
                                               const float* __restrict__ We0,
                                               const float* __restrict__ bd0,
                                               const float* __restrict__ We1,
                                               const float* __restrict__ bd1,
                                               const float* __restrict__ be1,
                                               const float* __restrict__ Wd1,
                                               const float* __restrict__ Wd0,
                                               u16* __restrict__ W1T,
                                               float* __restrict__ cv,
                                               u16* __restrict__ B2T,
                                               u16* __restrict__ xb,
                                               float* __restrict__ pp,
                                               float* __restrict__ xnp,
                                               float* __restrict__ wn) {
  __shared__ float smem[64 * 65];                 // 16.6 KB shared by all branches
  const int bid = blockIdx.x, t = threadIdx.x;
  if (bid < 128) {
    const int j = bid;
    float* ts  = smem;                            // 64*33
    float* bds = smem + 64 * 33;                  // 64
    float* red = smem + 64 * 33 + 64;             // 8*32
    const int k = t & 31, g = t >> 5;
    float cacc = 0.f;
    for (int db = 0; db < 12; ++db) {
      const float* src = We1 + (size_t)j * 24576 + db * 2048;  // 64 d x 32 k
#pragma unroll
      for (int i = 0; i < 8; ++i) {
        int e = t + i * 256;
        ts[(e >> 5) * 33 + (e & 31)] = src[e];
      }
      if (t < 64) bds[t] = bd1[(size_t)j * DDATA + db * 64 + t];
      __syncthreads();
#pragma unroll
      for (int i = 0; i < 8; ++i) {
        int e = t + i * 256;
        int kk = e >> 6, d = e & 63;
        W1T[(size_t)(j * 32 + kk) * DDATA + db * 64 + d] = f2bf(ts[d * 33 + kk]);
      }
#pragma unroll
      for (int q = 0; q < 8; ++q) {
        int d = g + 8 * q;
        cacc += ts[d * 33 + k] * bds[d];
      }
      __syncthreads();
    }
    red[g * 32 + k] = cacc;
    __syncthreads();
    if (g == 0) {
      float s = 0.f;
#pragma unroll
      for (int q = 0; q < 8; ++q) s += red[q * 32 + k];
      cv[j * 32 + k] = be1[j * 32 + k] - s;
    }
  } else if (bid < 944) {
    const int e2 = bid - 128;
    const int rb = e2 / 12, dbk = e2 % 12;
    const float* src; int r0, base;
    if (rb < 64)      { src = Wd1; r0 = rb * 64;        base = 0;    }
    else if (rb < 66) { src = Wd0; r0 = (rb - 64) * 64; base = 4096; }
    else              { src = bd1; r0 = (rb - 66) * 64; base = 4224; }
    const int d0 = dbk * 64;
#pragma unroll
    for (int i = 0; i < 16; ++i) {
      int e = t + i * 256;
      int ri = e >> 6, di = e & 63;
      smem[ri * 65 + di] = src[(size_t)(r0 + ri) * DDATA + d0 + di];
    }
    __syncthreads();
#pragma unroll
    for (int i = 0; i < 16; ++i) {
      int e = t + i * 256;
      int di = e >> 6, ri = e & 63;
      B2T[(size_t)(d0 + di) * KA2 + base + r0 + ri] = f2bf(smem[ri * 65 + di]);
    }
  } else if (bid < 952) {
    const int wb = bid - 944;                     // 16 j per block
    const int jj = wb * 16 + (t >> 4), s = t & 15;
    float acc = 0.f;
    for (int d = s; d < DDATA; d += 16) {
      float w = We0[(size_t)d * 128 + jj];
      acc += w * w;
    }
#pragma unroll
    for (int sh = 8; sh; sh >>= 1) acc += __shfl_xor(acc, sh, 64);
    if (s == 0) wn[jj] = sqrtf(acc);
  } else {
    const int bid2 = bid - 952;
    const int b0 = (bid2 & 63) * 32, z = bid2 >> 6;
    const int dbase = z * GZW;
    float* xs = smem;                             // 32*96 = 12 KB
#pragma unroll
    for (int i = 0; i < 3; ++i) {
      int idx = t + i * 256;                      // 32 rows x 24 float4
      int r = idx / 24, c4 = idx % 24;
      size_t go = (size_t)(b0 + r) * DDATA + dbase + c4 * 4;
      float4 v = *(const float4*)&x[go];
      ushort4 o;
      o.x = f2bf(v.x); o.y = f2bf(v.y); o.z = f2bf(v.z); o.w = f2bf(v.w);
      *(ushort4*)&xb[go] = o;                     // fused xcast
      float4 b4 = *(const float4*)&bd0[dbase + c4 * 4];
      v.x -= b4.x; v.y -= b4.y; v.z -= b4.z; v.w -= b4.w;
      *(float4*)&xs[r * GZW + c4 * 4] = v;
    }
    __syncthreads();
    const int jp = t & 63, rg = t >> 6;           // wave-uniform rg
    const int j0 = jp * 2;
    float ap[8][2], xq[8];
#pragma unroll
    for (int r = 0; r < 8; ++r) { ap[r][0] = ap[r][1] = xq[r] = 0.f; }
    for (int d = 0; d < GZW; d += 4) {
      float4 xv[8];
#pragma unroll
      for (int r = 0; r < 8; ++r)
        xv[r] = *(const float4*)&xs[(rg * 8 + r) * GZW + d];
#pragma unroll
      for (int dd = 0; dd < 4; ++dd) {
        float2 w2 = *(const float2*)&We0[(size_t)(dbase + d + dd) * 128 + j0];
#pragma unroll
        for (int r = 0; r < 8; ++r) {
          float xr = ((const float*)&xv[r])[dd];
          ap[r][0] += xr * w2.x;
          ap[r][1] += xr * w2.y;
          xq[r]    += xr * xr;
        }
      }
    }
#pragma unroll
    for (int r = 0; r < 8; ++r) {
      size_t o = ((size_t)z * B_SZ + b0 + rg * 8 + r) * 128 + j0;
      *(float2*)&pp[o] = make_float2(ap[r][0], ap[r][1]);
    }
    if (jp == 0) {
#pragma unroll
      for (int r = 0; r < 8; ++r)
        xnp[(size_t)z * B_SZ + b0 + rg * 8 + r] = xq[r];
    }
  }
}

// ==== k_gate2: reduce chunks, write acts0/gate, wave-coop exact fp64 fix-up ====
__global__ __launch_bounds__(256) void k_gate2(const float* __restrict__ pp,
                                               const float* __restrict__ xnp,
                                               const float* __restrict__ wn,
                                               const float* __restrict__ be0,
                                               const float* __restrict__ x,
                                               const float* __restrict__ We0,
                                               const float* __restrict__ bd0,
                                               u16* __restrict__ A2) {
  const int i = blockIdx.x * 256 + threadIdx.x;   // 262144
  const int b = i >> 7, j = i & 127;
  const int lane = threadIdx.x & 63;
  float p = be0[j], xn2 = 0.f;
#pragma unroll
  for (int z = 0; z < GZCH; ++z) {
    p   += pp[((size_t)z * B_SZ + b) * 128 + j];
    xn2 += xnp[(size_t)z * B_SZ + b];
  }
  const float tau = 1e-4f * sqrtf(xn2) * wn[j];
  size_t row = (size_t)b * KA2;
  A2[row + NJK + j]       = f2bf(p > 0.f ? p : 0.f);
  A2[row + NJK + 128 + j] = (p > 0.f) ? (u16)0x3F80 : (u16)0;
  // fp32 sign uncertain -> whole wave cooperates on exact fp64 recompute
  unsigned long long mask = __ballot(fabsf(p) <= tau);
  while (mask) {
    int src = (int)__builtin_ctzll(mask);
    mask &= mask - 1;
    int bb = __shfl(b, src, 64), jj = __shfl(j, src, 64);
    double acc = 0.0;
#pragma unroll
    for (int tt = 0; tt < 12; ++tt) {
      int d = lane + tt * 64;
      acc += (double)(x[(size_t)bb * DDATA + d] - bd0[d]) *
             (double)We0[(size_t)d * 128 + jj];
    }
#pragma unroll
    for (int s = 32; s; s >>= 1) acc += __shfl_xor(acc, s, 64);
    if (lane == src) {
      double pd = acc + (double)be0[jj];
      size_t rw = (size_t)bb * KA2;
      A2[rw + NJK + jj]       = f2bf(pd > 0.0 ? (float)pd : 0.f);
      A2[rw + NJK + 128 + jj] = (pd > 0.0) ? (u16)0x3F80 : (u16)0;
    }
  }
}

// ------ GEMM: C = A[M,K] * B^T[N,K], bf16 MFMA 16x16x32, BK=64, XOR-swizzled LDS ------
// EPI=1: gate_s/cv_s preloaded BEFORE K-loop; v = relu(v + c[gn]) * gate -> bf16x2 A2
// EPI=2: part[bz][gm][gn] = v  (split-K fp32, reduced by k_reduce)
template<int BM, int BN, int EPI>
__global__ __launch_bounds__(256) void k_gemm(const u16* __restrict__ A,
                                              const u16* __restrict__ Bm,
                                              int K, int Kc,
                                              float* __restrict__ outF,
                                              u16* __restrict__ A2,
                                              const float* __restrict__ cvec) {
  constexpr int WM = BM / 32, WN = BN / 32;
  __shared__ __align__(16) u16 As[BM * 64];
  __shared__ __align__(16) u16 Bs[BN * 64];
  __shared__ u16 gate_s[BM * 4];
  __shared__ float cv_s[BN];
  const int tid = threadIdx.x;
  const int bx = blockIdx.x, by = blockIdx.y, bz = blockIdx.z;
  const int kbase = bz * Kc;
  const u16* Ab = A  + (size_t)(by * BM) * K;
  const u16* Bb = Bm + (size_t)(bx * BN) * K;
  const int wave = tid >> 6, lane = tid & 63;
  const int wr = wave >> 1, wc = wave & 1;
  const int m0 = wr * (BM / 2), n0 = wc * (BN / 2);
  const int lm = lane & 15, qd = lane >> 4;

  if (EPI == 1) {
    // preload epilogue data up front (ready; in-loop barriers cover the sync)
    for (int e = tid; e < BM * 4; e += 256) {
      int r = e >> 2, q = e & 3;
      gate_s[e] = A2[(size_t)(by * BM + r) * KA2 + NJK + 128 + bx * 4 + q];
    }
    for (int e = tid; e < BN; e += 256) cv_s[e] = cvec[bx * BN + e];
  }

  f32x4 acc[WM][WN];
  const f32x4 zero = {0.f, 0.f, 0.f, 0.f};
  for (int mi = 0; mi < WM; ++mi)
    for (int ni = 0; ni < WN; ++ni) acc[mi][ni] = zero;

  for (int k0 = kbase; k0 < kbase + Kc; k0 += 64) {
#pragma unroll
    for (int i = 0; i < BM / 32; ++i) {
      int id = tid + 256 * i;
      int row = id >> 3, u = id & 7;
      gload16(Ab + (size_t)row * K + k0 + ((u ^ (row & 7)) * 8), &As[id * 8]);
    }
#pragma unroll
    for (int i = 0; i < BN / 32; ++i) {
      int id = tid + 256 * i;
      int row = id >> 3, u = id & 7;
      gload16(Bb + (size_t)row * K + k0 + ((u ^ (row & 7)) * 8), &Bs[id * 8]);
    }
    __syncthreads();
#pragma unroll
    for (int s = 0; s < 2; ++s) {
      const int swz = ((s << 2) + qd) ^ (lm & 7);
      bf16x8 af[WM], bfv[WN];
#pragma unroll
      for (int mi = 0; mi < WM; ++mi)
        af[mi] = *(const bf16x8*)&As[(m0 + mi * 16 + lm) * 64 + swz * 8];
#pragma unroll
      for (int ni = 0; ni < WN; ++ni)
        bfv[ni] = *(const bf16x8*)&Bs[(n0 + ni * 16 + lm) * 64 + swz * 8];
#pragma unroll
      for (int mi = 0; mi < WM; ++mi)
#pragma unroll
        for (int ni = 0; ni < WN; ++ni)
          acc[mi][ni] = __builtin_amdgcn_mfma_f32_16x16x32_bf16(af[mi], bfv[ni],
                                                                acc[mi][ni], 0, 0, 0);
    }
    __syncthreads();
  }

  const int rb = qd * 4;
#pragma unroll
  for (int mi = 0; mi < WM; ++mi) {
#pragma unroll
    for (int ni = 0; ni < WN; ++ni) {
#pragma unroll
      for (int r = 0; r < 4; ++r) {
        int ml = m0 + mi * 16 + rb + r;
        int nl = n0 + ni * 16 + lm;
        int gm = by * BM + ml;
        int gn = bx * BN + nl;
        float v = acc[mi][ni][r];
        if (EPI == 1) {
          v += cv_s[nl];
          v = v > 0.f ? v : 0.f;
          u16 gbit = gate_s[ml * 4 + (nl >> 5)];
          v = gbit ? v : 0.f;
          float vn = __shfl_xor(v, 1, 64);        // pack even/odd columns
          if ((lm & 1) == 0) {
            unsigned pk = (unsigned)f2bf(v) | ((unsigned)f2bf(vn) << 16);
            *(unsigned*)&A2[(size_t)gm * KA2 + gn] = pk;
          }
        } else {
          outF[((size_t)bz * B_SZ + gm) * DDATA + gn] = v;
        }
      }
    }
  }
}

// ---------------- reduce split-K partials + bias ----------------
__global__ __launch_bounds__(256) void k_reduce(const float* __restrict__ part,
                                                const float* __restrict__ bias,
                                                float* __restrict__ out) {
  const int N4 = B_SZ * DDATA / 4;
  int i = blockIdx.x * 256 + threadIdx.x;
  const float4* p4 = (const float4*)part;
  float4 s = p4[i];
#pragma unroll
  for (int z = 1; z < SPLITK; ++z) {
    float4 t = p4[i + z * N4];
    s.x += t.x; s.y += t.y; s.z += t.z; s.w += t.w;
  }
  float4 b = ((const float4*)bias)[i % (DDATA / 4)];
  s.x += b.x; s.y += b.y; s.z += b.z; s.w += b.w;
  ((float4*)out)[i] = s;
}

extern "C" void kernel_launch(void* const* d_in, const int* in_sizes, int n_in,
                              void* d_out, int out_size, void* d_ws, size_t ws_size,
                              hipStream_t stream) {
  const float* x   = (const float*)d_in[0];
  const float* We0 = (const float*)d_in[1];
  const float* be0 = (const float*)d_in[2];
  const float* Wd0 = (const float*)d_in[3];
  const float* bd0 = (const float*)d_in[4];
  const float* We1 = (const float*)d_in[5];
  const float* be1 = (const float*)d_in[6];
  const float* Wd1 = (const float*)d_in[7];
  const float* bd1 = (const float*)d_in[8];
  float* out = (float*)d_out;

  uint8_t* ws = (uint8_t*)d_ws;
  size_t off = 0;
  auto carve = [&](size_t bytes) {
    uint8_t* p = ws + off;
    off += (bytes + 255) & ~(size_t)255;
    return p;
  };
  u16*    A2   = (u16*)carve((size_t)B_SZ * KA2 * 2);
  u16*    xb   = (u16*)carve((size_t)B_SZ * DDATA * 2);
  u16*    W1T  = (u16*)carve((size_t)NJK * DDATA * 2);
  u16*    B2T  = (u16*)carve((size_t)DDATA * KA2 * 2);
  float*  cv   = (float*)carve((size_t)NJK * 4);
  float*  part = (float*)carve((size_t)SPLITK * B_SZ * DDATA * 4);   // 12.6 MB
  float*  pp   = (float*)carve((size_t)GZCH * B_SZ * 128 * 4);       // 8.4 MB
  float*  xnp  = (float*)carve((size_t)GZCH * B_SZ * 4);             // 64 KB
  float*  wn   = (float*)carve(128 * 4);

  // all input-independent prep + gate partials, one kernel (pipes overlap)
  k_front <<<1464, 256, 0, stream>>>(x, We0, bd0, We1, bd1, be1, Wd1, Wd0,
                                     W1T, cv, B2T, xb, pp, xnp, wn);
  // gate reduce + in-kernel exact fix-up
  k_gate2 <<<1024, 256, 0, stream>>>(pp, xnp, wn, be0, x, We0, bd0, A2);
  // GEMM1: acts1 -> A2[:, 0..4095]   (M=2048, N=4096, K=768)
  k_gemm<128, 128, 1><<<dim3(32, 16, 1), 256, 0, stream>>>(xb, W1T, DDATA, DDATA,
                                                           nullptr, A2, cv);
  // GEMM2 split-K: part[z] = A2 @ B2 over K-chunk z   (M=2048, N=768, K=4352)
  // BM=32 -> grid (6,64,2)=768 blocks (3/CU) for tail-latency hiding
  k_gemm<32, 128, 2><<<dim3(6, 64, SPLITK), 256, 0, stream>>>(A2, B2T, KA2, KC2,
                                                              part, nullptr, nullptr);
  k_reduce<<<1536, 256, 0, stream>>>(part, bd0, out);
}